// Round 4
// baseline (342.685 us; speedup 1.0000x reference)
//
#include <hip/hip_runtime.h>
#include <hip/hip_bf16.h>
#include <math.h>

#define IC 512
#define OC 512
#define STYLE 512
#define BB 8
#define H_ 64
#define W_ 64
#define HW 4096
#define HP 66          // padded rows (zero row above and below)
#define KC 32          // channel chunk per MFMA K-step
#define NCHUNK 16
#define USTRIDE 1056   // bytes per u-granule plane in conv LDS: 66 cols * 16B
#define ROWSTRIDE 4224 // 4 * USTRIDE
#define XROWS 18       // staged input rows per block (16 outputs + halo)
#define BUFX (XROWS * ROWSTRIDE)   // 76032 B per x buffer

typedef __attribute__((ext_vector_type(8))) __bf16 bf16x8;
typedef __attribute__((ext_vector_type(4))) float floatx4;

static __device__ __forceinline__ unsigned short f2bf(float f) {
    unsigned u = __builtin_bit_cast(unsigned, f);
    unsigned r = u + 0x7FFFu + ((u >> 16) & 1u);   // RNE
    return (unsigned short)(r >> 16);
}

// async global->LDS DMA, 16B per lane. dst is wave-uniform base; HW writes lane i at dst + i*16.
static __device__ __forceinline__ void gload_lds16(const unsigned short* g, unsigned char* l) {
    __builtin_amdgcn_global_load_lds((const __attribute__((address_space(1))) unsigned int*)g,
                                     (__attribute__((address_space(3))) unsigned int*)l,
                                     16, 0, 0);
}

// ---------------- K1: s[b,i] = MOD_SCALE * style[b,:]·(mod_weight + fcB@fcA^T)[i,:] + biases
__global__ void k_style(const float* __restrict__ style, const float* __restrict__ mod_weight,
                        const float* __restrict__ mod_bias, const float* __restrict__ fc_lora_A,
                        const float* __restrict__ fc_lora_B, const float* __restrict__ fc_lora_bias,
                        float* __restrict__ s_out) {
    int b = blockIdx.y;
    int i = blockIdx.x * 16 + (threadIdx.x >> 4);
    int jg = threadIdx.x & 15;
    float4 fb = *(const float4*)&fc_lora_B[i * 4];
    const float* st = style + b * STYLE;
    const float* mw = mod_weight + (size_t)i * STYLE;
    float acc = 0.f;
    for (int j = jg * 32; j < jg * 32 + 32; ++j) {
        float4 fa = *(const float4*)&fc_lora_A[j * 4];
        float w = mw[j] + fb.x * fa.x + fb.y * fa.y + fb.z * fa.z + fb.w * fa.w;
        acc += st[j] * w;
    }
    #pragma unroll
    for (int off = 8; off; off >>= 1) acc += __shfl_down(acc, off, 16);
    if (jg == 0) {
        float mod_scale = 1.0f / sqrtf((float)STYLE);
        s_out[b * IC + i] = mod_scale * acc + mod_bias[i] + fc_lora_bias[i];
    }
}

// ---------------- K2: w5 = weight + relu(A·relu(B·inst)); wb swizzled for MFMA A-frags; W2[o][i]
// wb layout: [t(9)][ot(8)][mt(4)][ci(16)][lane(64)][8]
__global__ void k_weight(const float* __restrict__ weight, const float* __restrict__ llB,
                         const float* __restrict__ llBinst, const float* __restrict__ llA,
                         unsigned short* __restrict__ wb, float* __restrict__ W2) {
    int gid = blockIdx.x * 256 + threadIdx.x;      // 262144
    int o = gid >> 9, i = gid & 511;
    float4 vB = *(const float4*)&llB[o * 4];
    float4 vA = *(const float4*)&llA[i * 4];
    const float* wrow = weight + (size_t)(o * IC + i) * 9;
    int lane = ((i >> 3) & 3) * 16 + (o & 15);
    size_t wbase = (((size_t)((o >> 6) * 4 + ((o >> 4) & 3)) * 16 + (i >> 5)) * 64 + lane) * 8 + (i & 7);
    float w2 = 0.f;
    #pragma unroll
    for (int k = 0; k < 9; ++k) {
        float wadd = 0.f;
        #pragma unroll
        for (int bb = 0; bb < 4; ++bb) {
            float bm = vB.x * llBinst[(bb * 4 + 0) * 9 + k] + vB.y * llBinst[(bb * 4 + 1) * 9 + k]
                     + vB.z * llBinst[(bb * 4 + 2) * 9 + k] + vB.w * llBinst[(bb * 4 + 3) * 9 + k];
            bm = fmaxf(bm, 0.f);
            float a = (bb == 0) ? vA.x : (bb == 1) ? vA.y : (bb == 2) ? vA.z : vA.w;
            wadd += a * bm;
        }
        wadd = fmaxf(wadd, 0.f);
        float w5 = wrow[k] + wadd;                 // LORA_ALPHA_CONV = 1
        wb[(size_t)k * 262144 + wbase] = f2bf(w5);
        w2 += w5 * w5;
    }
    W2[gid] = w2;
}

// ---------------- K3: scale[b][o] = CONV_SCALE * rsqrt(CONV_SCALE^2 * sum_i W2[o,i]*s[b,i]^2 + eps)
__global__ void k_scale(const float* __restrict__ W2, const float* __restrict__ s,
                        float* __restrict__ scale) {
    int b = blockIdx.y;
    int o = blockIdx.x * 16 + (threadIdx.x >> 4);
    int jg = threadIdx.x & 15;
    const float* w2r = W2 + (size_t)o * IC;
    const float* sr = s + b * IC;
    float acc = 0.f;
    for (int i = jg * 32; i < jg * 32 + 32; ++i) { float sv = sr[i]; acc += w2r[i] * sv * sv; }
    #pragma unroll
    for (int off = 8; off; off >>= 1) acc += __shfl_down(acc, off, 16);
    if (jg == 0) {
        float cs = 1.0f / sqrtf((float)(IC * 9));
        scale[b * OC + o] = cs * rsqrtf(cs * cs * acc + 1e-8f);
    }
}

// ---------------- K4: NCHW fp32 -> xm[b][hp][ci(16)][u(4)][w(64)][8ch] bf16, modulated by s
__global__ void k_stage_x(const float* __restrict__ x, const float* __restrict__ s,
                          unsigned short* __restrict__ xm) {
    __shared__ float tile[128 * 65];
    int cc = blockIdx.x;   // 0..3 (128-channel chunk)
    int hp = blockIdx.y;   // 0..65
    int b  = blockIdx.z;
    int c0 = cc * 128;
    int tid = threadIdx.x;
    if (hp == 0 || hp == HP - 1) {
        unsigned short* dst = xm + (size_t)(b * HP + hp) * 32768 + cc * 8192;
        uint4 z = make_uint4(0, 0, 0, 0);
        #pragma unroll
        for (int p = 0; p < 4; ++p)
            *(uint4*)(dst + (size_t)(p * 256 + tid) * 8) = z;
        return;
    }
    int h = hp - 1;
    const float* xin = x + (((size_t)b * IC + c0) * H_ + h) * W_;
    #pragma unroll
    for (int p = 0; p < 32; ++p) {
        int idx = p * 256 + tid;
        int c = idx >> 6, w = idx & 63;
        tile[c * 65 + w] = xin[(size_t)c * HW + w];
    }
    __syncthreads();
    const float* sb = s + b * IC + c0;
    #pragma unroll
    for (int p = 0; p < 4; ++p) {
        int idx = p * 256 + tid;               // 0..1023
        int cil = idx >> 8;                    // local ci 0..3
        int u   = (idx >> 6) & 3;
        int w   = idx & 63;
        int cb  = cil * 32 + u * 8;
        unsigned int packed[4];
        #pragma unroll
        for (int k = 0; k < 4; ++k) {
            unsigned lo = f2bf(tile[(cb + 2 * k) * 65 + w] * sb[cb + 2 * k]);
            unsigned hi = f2bf(tile[(cb + 2 * k + 1) * 65 + w] * sb[cb + 2 * k + 1]);
            packed[k] = lo | (hi << 16);
        }
        size_t g = (((size_t)(b * HP + hp) * 16 + (cc * 4 + cil)) * 4 + u) * 64 + w;
        *(uint4*)(xm + g * 8) = make_uint4(packed[0], packed[1], packed[2], packed[3]);
    }
}

// ---------------- K5: conv. 512-thread block = 64 oc x (16 rows x 64 cols). 8 waves; each wave
// computes 2 output rows x 64 oc (acc[2][4][4]) so every af weight-load feeds 8 MFMAs (was 4):
// halves the redundant weight L2 traffic (2.3 GB -> 1.18 GB). Grid = 256 = exactly 1 block/CU,
// 2 waves/SIMD. 2-phase pipeline: barrier -> DMA(ci+1) -> compute(ci). ot = wgid%8 pins each
// 576 KB weight slice to one XCD's L2 (T1).
__global__ __launch_bounds__(512, 2) void k_conv(const unsigned short* __restrict__ wb,
                                                 const unsigned short* __restrict__ xm,
                                                 const float* __restrict__ scale,
                                                 float* __restrict__ out) {
    __shared__ unsigned char xs[2 * BUFX];         // 152064 B; epilogue reuses (34816 B)
    const int tid = threadIdx.x;                   // 0..511
    const int wave = tid >> 6, lane = tid & 63;    // 8 waves
    const int l16 = lane & 15, lq = lane >> 4;
    const int wgid = blockIdx.x;        // 0..255
    const int ot = wgid & 7;            // 0..7  -> pinned to XCD (wgid % 8)
    const int r  = wgid >> 3;           // 0..31
    const int ht = r & 3;               // 0..3
    const int b  = r >> 2;              // 0..7
    const int om = ot * 64;
    const int h0 = ht * 16;             // block's first output row
    const int r0 = wave * 2;            // wave's first row (block-relative)

    // zero border col-granules (cols 0 and 65, all 18 rows, all u, BOTH buffers): 288 x 16B
    if (tid < 288) {
        int bsel = tid >= 144;
        int t144 = tid - bsel * 144;
        int row = t144 >> 3;            // 0..17
        int rem = t144 & 7;
        int u = rem >> 1;
        int side = rem & 1;
        uint4 z = make_uint4(0, 0, 0, 0);
        *(uint4*)(xs + (size_t)bsel * BUFX + (size_t)row * ROWSTRIDE + u * USTRIDE + side * 65 * 16) = z;
    }

    floatx4 acc[2][4][4];
    #pragma unroll
    for (int rr = 0; rr < 2; ++rr)
        #pragma unroll
        for (int mt = 0; mt < 4; ++mt)
            #pragma unroll
            for (int nt = 0; nt < 4; ++nt)
                acc[rr][mt][nt] = (floatx4){0.f, 0.f, 0.f, 0.f};

    // x staging: 72 granule-planes (18 rows x 4 u) split 9 per wave; DMA writes lanes at dst+lane*16
    // (cols 1..64; border cols 0/65 hold the pre-written zeros).
    const unsigned short* xmb = xm + (size_t)b * HP * 32768;
    // weights: swizzled so per-wave load is base + lane*16B (coalesced)
    const unsigned short* wlb = wb + (size_t)ot * 32768 + (size_t)lane * 8;

    // prologue: DMA chunk 0 into buffer 0
    #pragma unroll
    for (int j = 0; j < 9; ++j) {
        const int g = wave * 9 + j;
        const int row = g >> 2, u = g & 3;
        gload_lds16(xmb + ((((size_t)(h0 + row) * 16 + 0) * 4 + u) * 64 + lane) * 8,
                    xs + (size_t)row * ROWSTRIDE + u * USTRIDE + 16);
    }

    int cur = 0;
    for (int ci = 0; ci < NCHUNK; ++ci) {
        __syncthreads();                // drains DMA for buf[cur] (implicit vmcnt(0)) + makes it visible
        if (ci + 1 < NCHUNK) {          // stage next chunk into the other buffer; in flight across compute
            #pragma unroll
            for (int j = 0; j < 9; ++j) {
                const int g = wave * 9 + j;
                const int row = g >> 2, u = g & 3;
                gload_lds16(xmb + ((((size_t)(h0 + row) * 16 + (ci + 1)) * 4 + u) * 64 + lane) * 8,
                            xs + (size_t)(cur ^ 1) * BUFX + (size_t)row * ROWSTRIDE + u * USTRIDE + 16);
            }
        }
        const unsigned char* buf = xs + (size_t)cur * BUFX;
        const unsigned short* wlc = wlb + (size_t)ci * 512;
        #pragma unroll
        for (int kh = 0; kh < 3; ++kh) {
            #pragma unroll
            for (int dw = 0; dw < 3; ++dw) {
                const int t = kh * 3 + dw;
                bf16x8 af[4], bva[4], bvb[4];
                #pragma unroll
                for (int mt = 0; mt < 4; ++mt)
                    af[mt] = *(const bf16x8*)(wlc + (size_t)t * 262144 + mt * 8192);
                #pragma unroll
                for (int nt = 0; nt < 4; ++nt) {
                    bva[nt] = *(const bf16x8*)(buf + (size_t)(r0 + kh) * ROWSTRIDE + lq * USTRIDE
                                               + (nt * 16 + l16 + dw) * 16);
                    bvb[nt] = *(const bf16x8*)(buf + (size_t)(r0 + 1 + kh) * ROWSTRIDE + lq * USTRIDE
                                               + (nt * 16 + l16 + dw) * 16);
                }
                #pragma unroll
                for (int mt = 0; mt < 4; ++mt)
                    #pragma unroll
                    for (int nt = 0; nt < 4; ++nt) {
                        acc[0][mt][nt] = __builtin_amdgcn_mfma_f32_16x16x32_bf16(af[mt], bva[nt], acc[0][mt][nt], 0, 0, 0);
                        acc[1][mt][nt] = __builtin_amdgcn_mfma_f32_16x16x32_bf16(af[mt], bvb[nt], acc[1][mt][nt], 0, 0, 0);
                    }
            }
        }
        cur ^= 1;
    }

    // ---- epilogue: scale, then stage through LDS for fully-coalesced float4 stores
    __syncthreads();                    // all waves done with both x buffers
    float* ebuf = (float*)xs + wave * 1088;        // 16 oc-rows x 68 floats per wave
    const float* scb = scale + b * OC + om;
    #pragma unroll
    for (int rr = 0; rr < 2; ++rr) {
        const int h = h0 + r0 + rr;
        #pragma unroll
        for (int mt = 0; mt < 4; ++mt) {
            float4 sc = *(const float4*)&scb[mt * 16 + lq * 4];
            const float* scp = (const float*)&sc;
            #pragma unroll
            for (int nt = 0; nt < 4; ++nt)
                #pragma unroll
                for (int r2 = 0; r2 < 4; ++r2)
                    ebuf[(lq * 4 + r2) * 68 + nt * 16 + l16] = acc[rr][mt][nt][r2] * scp[r2];
            __syncthreads();            // uniform; guarantees write->read ordering
            #pragma unroll
            for (int q = 0; q < 4; ++q) {
                int rq = q * 4 + (lane >> 4);
                int c0 = (lane & 15) * 4;
                float4 v = *(float4*)&ebuf[rq * 68 + c0];
                *(float4*)&out[((size_t)(b * OC + om + mt * 16 + rq)) * HW + h * W_ + c0] = v;
            }
            __syncthreads();            // reads done before next iteration's writes
        }
    }
}

extern "C" void kernel_launch(void* const* d_in, const int* in_sizes, int n_in,
                              void* d_out, int out_size, void* d_ws, size_t ws_size,
                              hipStream_t stream) {
    const float* input   = (const float*)d_in[0];
    const float* style   = (const float*)d_in[1];
    const float* weight  = (const float*)d_in[2];
    const float* llB     = (const float*)d_in[3];
    const float* llBinst = (const float*)d_in[4];
    const float* llA     = (const float*)d_in[5];
    const float* mod_w   = (const float*)d_in[6];
    const float* mod_b   = (const float*)d_in[7];
    const float* fcA     = (const float*)d_in[8];
    const float* fcB     = (const float*)d_in[9];
    const float* fcBias  = (const float*)d_in[10];
    float* out = (float*)d_out;

    char* ws = (char*)d_ws;
    float* s_ws            = (float*)(ws + 0);                  // 16 KB
    float* scale_ws        = (float*)(ws + 16384);              // 16 KB
    float* W2_ws           = (float*)(ws + 32768);              // 1 MB
    unsigned short* wb_ws  = (unsigned short*)(ws + 32768 + 1048576);          // 4.72 MB
    unsigned short* xm_ws  = (unsigned short*)(ws + 32768 + 1048576 + 4718592); // 34.6 MB

    k_style<<<dim3(32, 8), 256, 0, stream>>>(style, mod_w, mod_b, fcA, fcB, fcBias, s_ws);
    k_weight<<<1024, 256, 0, stream>>>(weight, llB, llBinst, llA, wb_ws, W2_ws);
    k_scale<<<dim3(32, 8), 256, 0, stream>>>(W2_ws, s_ws, scale_ws);
    k_stage_x<<<dim3(4, 66, 8), 256, 0, stream>>>(input, s_ws, xm_ws);
    k_conv<<<256, 512, 0, stream>>>(wb_ws, xm_ws, scale_ws, out);
}